// Round 2
// baseline (1734.784 us; speedup 1.0000x reference)
//
#include <hip/hip_runtime.h>

// ---------------------------------------------------------------------------
// PAM_Module_Dep: dual-modality position attention.
//   q = [conv1x1(x,wq); conv1x1(dep,wqd)]  -> [B,128,N]
//   k = [conv1x1(x,wk); conv1x1(dep,wkd)]  -> [B,128,N]
//   e[b,i,j] = sum_d q[d,i] k[d,j]; attn = softmax_j(e)
//   v = conv1x1(x,wv) [B,512,N]; out = gamma * (attn @ v^T) + x
// B=4, C=512, N=4096 (64x64), CQ=64.
//
// Round 2: input dtype is ambiguous (template says fp32 per reference; test
// labels say bf16). Round-1 NaN is exactly the fp32-read-as-bf16 symptom.
// => runtime dtype detection (first 256 u16 of x as bf16: count plausible
//    magnitudes; bf16 data ~256/256 in range, fp32-as-bf16 ~151/256).
// => unified compute path: inputs split to hi/lo bf16; fp32 mode uses
//    3-MFMA split product (error ~2^-16), bf16 mode uses 1 MFMA (exact).
// => output dtype coupled to input dtype.
// ---------------------------------------------------------------------------

typedef __attribute__((ext_vector_type(8))) short bf16x8;
typedef __attribute__((ext_vector_type(4))) float f32x4;

__device__ __forceinline__ float bf2f(unsigned short u) {
  return __builtin_bit_cast(float, (unsigned int)u << 16);
}
__device__ __forceinline__ unsigned short f2bf(float f) {
  unsigned int u = __builtin_bit_cast(unsigned int, f);
  u = u + 0x7fffu + ((u >> 16) & 1u);   // RNE
  return (unsigned short)(u >> 16);
}
__device__ __forceinline__ float bflo(unsigned int u) {
  return __builtin_bit_cast(float, u << 16);
}
__device__ __forceinline__ float bfhi(unsigned int u) {
  return __builtin_bit_cast(float, u & 0xffff0000u);
}

// Returns 1 if x looks like fp32 data, 0 if bf16. Wave-uniform, deterministic.
__device__ __forceinline__ int detect_fp32_mode(const void* xv) {
  const unsigned int* p = (const unsigned int*)xv;
  const int lane = threadIdx.x & 63;
  const unsigned int w0 = p[lane];
  const unsigned int w1 = p[64 + lane];
  int cnt = 0;
  const unsigned short us[4] = {
      (unsigned short)(w0 & 0xffffu), (unsigned short)(w0 >> 16),
      (unsigned short)(w1 & 0xffffu), (unsigned short)(w1 >> 16)};
#pragma unroll
  for (int h = 0; h < 4; ++h) {
    const float a = fabsf(bf2f(us[h]));
    cnt += (a > 9.0e-13f && a < 32.0f) ? 1 : 0;   // x ~ N(0,1): always true
  }
#pragma unroll
  for (int mm = 32; mm >= 1; mm >>= 1) cnt += __shfl_xor(cnt, mm, 64);
  return cnt < 220;
}

// ---------------------------------------------------------------------------
// prep: canonicalize weights into ws as split hi/lo bf16; biases+gamma fp32.
// Wcat row order: wq[0:64) wqd[64:128) wk[128:192) wkd[192:256) wv[256:768).
// ---------------------------------------------------------------------------
__global__ __launch_bounds__(256) void prep_kernel(
    const void* wq, const void* bq, const void* wqd, const void* bqd,
    const void* wk, const void* bk, const void* wkd, const void* bkd,
    const void* wv, const void* bv, const void* gam, const void* x,
    unsigned short* __restrict__ Whi, unsigned short* __restrict__ Wlo,
    float* __restrict__ Bcat, float* __restrict__ gamF)
{
  const int fp32mode = detect_fp32_mode(x);
  const int row = blockIdx.x;                    // 0..767
  const void* src; const void* bsrc; int srow;
  if (row < 64)       { src = wq;  bsrc = bq;  srow = row; }
  else if (row < 128) { src = wqd; bsrc = bqd; srow = row - 64; }
  else if (row < 192) { src = wk;  bsrc = bk;  srow = row - 128; }
  else if (row < 256) { src = wkd; bsrc = bkd; srow = row - 192; }
  else                { src = wv;  bsrc = bv;  srow = row - 256; }
  for (int c = threadIdx.x; c < 512; c += 256) {
    const float v = fp32mode ? ((const float*)src)[(size_t)srow * 512 + c]
                             : bf2f(((const unsigned short*)src)[(size_t)srow * 512 + c]);
    const unsigned short h = f2bf(v);
    Whi[(size_t)row * 512 + c] = h;
    Wlo[(size_t)row * 512 + c] = f2bf(v - bf2f(h));
  }
  if (threadIdx.x == 0) {
    Bcat[row] = fp32mode ? ((const float*)bsrc)[srow]
                         : bf2f(((const unsigned short*)bsrc)[srow]);
    if (row == 0)
      gamF[0] = fp32mode ? ((const float*)gam)[0]
                         : bf2f(((const unsigned short*)gam)[0]);
  }
}

// ---------------------------------------------------------------------------
// Projection GEMM tile: D = Wcat[wrow0:+16, 512] * X[512, 16] (+bias).
// A-frag: A[m=lane&15][k=quad*8+j]; B-frag: B[k=quad*8+j][n=lane&15];
// C/D: col=lane&15 (n), row=quad*4+reg.
// fp32 mode: value = hi + lo (split bf16); product via 3 MFMAs (hh, hl, lh).
// ---------------------------------------------------------------------------
__device__ __forceinline__ void do_tile(
    const unsigned short* __restrict__ Whi, const unsigned short* __restrict__ Wlo,
    const float* __restrict__ Bcat,
    const unsigned short* Xhi, const unsigned short* Xlo, int fp32mode,
    int wrow0, int kind, int d0,
    int b, int n0, int nsub, int l15, int quad,
    float* __restrict__ Q, float* __restrict__ K, unsigned short* __restrict__ V)
{
  f32x4 acc;
#pragma unroll
  for (int r = 0; r < 4; ++r) acc[r] = Bcat[wrow0 + quad * 4 + r];
  const unsigned short* whi = Whi + (size_t)(wrow0 + l15) * 512;
  const unsigned short* wlo = Wlo + (size_t)(wrow0 + l15) * 512;
  const unsigned short* xhi = Xhi + (nsub * 16 + l15) * 520;
  const unsigned short* xlo = Xlo + (nsub * 16 + l15) * 520;
#pragma unroll
  for (int ks = 0; ks < 16; ++ks) {
    const bf16x8 ah = *(const bf16x8*)(whi + ks * 32 + quad * 8);
    const bf16x8 bh = *(const bf16x8*)(xhi + ks * 32 + quad * 8);
    acc = __builtin_amdgcn_mfma_f32_16x16x32_bf16(ah, bh, acc, 0, 0, 0);
    if (fp32mode) {
      const bf16x8 al_ = *(const bf16x8*)(wlo + ks * 32 + quad * 8);
      const bf16x8 bl  = *(const bf16x8*)(xlo + ks * 32 + quad * 8);
      acc = __builtin_amdgcn_mfma_f32_16x16x32_bf16(ah, bl, acc, 0, 0, 0);
      acc = __builtin_amdgcn_mfma_f32_16x16x32_bf16(al_, bh, acc, 0, 0, 0);
    }
  }
  const int n = n0 + nsub * 16 + l15;
  if (kind == 0) {                       // Q fp32 [b][n][128]
    *(f32x4*)(Q + (((size_t)b << 12) + n) * 128 + d0 + quad * 4) = acc;
  } else if (kind == 1) {                // K fp32 [b][d][n]
#pragma unroll
    for (int r = 0; r < 4; ++r)
      K[((size_t)b * 128 + d0 + quad * 4 + r) * 4096 + n] = acc[r];
  } else {                               // V bf16 [b][n][512]
    ushort4 pk;
    pk.x = f2bf(acc[0]); pk.y = f2bf(acc[1]);
    pk.z = f2bf(acc[2]); pk.w = f2bf(acc[3]);
    *(ushort4*)(V + (((size_t)b << 12) + n) * 512 + d0 + quad * 4) = pk;
  }
}

__global__ __launch_bounds__(256) void proj_kernel(
    const void* __restrict__ x, const void* __restrict__ dep,
    const unsigned short* __restrict__ Whi, const unsigned short* __restrict__ Wlo,
    const float* __restrict__ Bcat,
    float* __restrict__ Q, float* __restrict__ K, unsigned short* __restrict__ V)
{
  __shared__ unsigned short Xhi[32 * 520];   // [n in tile][c], 33.3 KB
  __shared__ unsigned short Xlo[32 * 520];
  const int fp32mode = detect_fp32_mode(x);
  const int tid  = threadIdx.x;
  const int lane = tid & 63;
  const int wave = tid >> 6;
  const int l15  = lane & 15;
  const int quad = lane >> 4;
  const int nsub = wave & 1;
  const int rgrp = wave >> 1;
  const int b  = blockIdx.y;
  const int n0 = blockIdx.x * 32;

  const int cbase = tid >> 4;          // 0..15
  const int nn    = (tid & 15) * 2;

  // ---- stage x tile (transpose + split hi/lo) ----
  for (int r = 0; r < 32; ++r) {
    const int c = cbase + r * 16;
    const size_t off = (((size_t)b * 512 + c) << 12) + n0 + nn;
    float v0, v1;
    if (fp32mode) {
      const float2 f2 = *(const float2*)((const float*)x + off);
      v0 = f2.x; v1 = f2.y;
    } else {
      const unsigned int v2 = *(const unsigned int*)((const unsigned short*)x + off);
      v0 = bflo(v2 & 0xffffu); v1 = bflo(v2 >> 16);
    }
    const unsigned short h0 = f2bf(v0), h1 = f2bf(v1);
    Xhi[nn * 520 + c]       = h0;
    Xhi[(nn + 1) * 520 + c] = h1;
    Xlo[nn * 520 + c]       = f2bf(v0 - bf2f(h0));
    Xlo[(nn + 1) * 520 + c] = f2bf(v1 - bf2f(h1));
  }
  __syncthreads();

  // ---- stage-1 rows (from x): 40 tiles = wq(4) | wk(4) | wv(32) ----
  for (int rt = rgrp; rt < 40; rt += 2) {
    if (rt < 4)
      do_tile(Whi, Wlo, Bcat, Xhi, Xlo, fp32mode, rt * 16,             0, rt * 16,
              b, n0, nsub, l15, quad, Q, K, V);
    else if (rt < 8)
      do_tile(Whi, Wlo, Bcat, Xhi, Xlo, fp32mode, 128 + (rt - 4) * 16, 1, (rt - 4) * 16,
              b, n0, nsub, l15, quad, Q, K, V);
    else
      do_tile(Whi, Wlo, Bcat, Xhi, Xlo, fp32mode, 256 + (rt - 8) * 16, 2, (rt - 8) * 16,
              b, n0, nsub, l15, quad, Q, K, V);
  }
  __syncthreads();

  // ---- restage with dep ----
  for (int r = 0; r < 32; ++r) {
    const int c = cbase + r * 16;
    const size_t off = (((size_t)b * 512 + c) << 12) + n0 + nn;
    float v0, v1;
    if (fp32mode) {
      const float2 f2 = *(const float2*)((const float*)dep + off);
      v0 = f2.x; v1 = f2.y;
    } else {
      const unsigned int v2 = *(const unsigned int*)((const unsigned short*)dep + off);
      v0 = bflo(v2 & 0xffffu); v1 = bflo(v2 >> 16);
    }
    const unsigned short h0 = f2bf(v0), h1 = f2bf(v1);
    Xhi[nn * 520 + c]       = h0;
    Xhi[(nn + 1) * 520 + c] = h1;
    Xlo[nn * 520 + c]       = f2bf(v0 - bf2f(h0));
    Xlo[(nn + 1) * 520 + c] = f2bf(v1 - bf2f(h1));
  }
  __syncthreads();

  // ---- stage-2 rows (from dep): wqd(4) | wkd(4), d-base 64 ----
  for (int rt = rgrp; rt < 8; rt += 2) {
    if (rt < 4)
      do_tile(Whi, Wlo, Bcat, Xhi, Xlo, fp32mode, 64 + rt * 16,        0, 64 + rt * 16,
              b, n0, nsub, l15, quad, Q, K, V);
    else
      do_tile(Whi, Wlo, Bcat, Xhi, Xlo, fp32mode, 192 + (rt - 4) * 16, 1, 64 + (rt - 4) * 16,
              b, n0, nsub, l15, quad, Q, K, V);
  }
}

// ---------------------------------------------------------------------------
// Flash attention, fp32 vector. Block = (b, 16 Q-rows). 256 threads.
// Wave w owns e_buf rows 4w..4w+3 in every phase -> barrier-free main loop.
// ---------------------------------------------------------------------------
__global__ __launch_bounds__(256) void attn_kernel(
    const float* __restrict__ Q, const float* __restrict__ K,
    const unsigned short* __restrict__ V,
    const void* __restrict__ x,
    const float* __restrict__ gamF,
    void* __restrict__ outp)
{
  __shared__ float q_t[16 * 128];      // 8 KB
  __shared__ float e_buf[16 * 257];    // 16.4 KB
  const int fp32mode = detect_fp32_mode(x);
  const int tid    = threadIdx.x;
  const int b      = blockIdx.y;
  const int n0     = blockIdx.x * 16;
  const int c_lane = tid & 63;
  const int islot  = tid >> 6;
  const int i_m    = tid >> 4;
  const int l16    = tid & 15;

  for (int idx = tid; idx < 16 * 128; idx += 256)
    q_t[idx] = Q[(((size_t)b << 12) + n0 + (idx >> 7)) * 128 + (idx & 127)];
  __syncthreads();

  float acc[4][8];
#pragma unroll
  for (int ii = 0; ii < 4; ++ii)
#pragma unroll
    for (int cc = 0; cc < 8; ++cc) acc[ii][cc] = 0.f;
  float m_run = -3.0e38f, l_run = 0.f;

  const float* kb = K + (size_t)b * 128 * 4096 + c_lane;
  const uint4* vb = (const uint4*)V;   // one uint4 = 8 bf16 V channels

  for (int jc = 0; jc < 16; ++jc) {
    const int j0 = jc * 256;
    // ---- energy: e[i][j] = q_i . k_j, fp32 ----
    float e[4][4] = {};
    const float* kp = kb + j0;
#pragma unroll 2
    for (int d = 0; d < 128; ++d) {
      const float k0 = kp[d * 4096];
      const float k1 = kp[d * 4096 + 64];
      const float k2 = kp[d * 4096 + 128];
      const float k3 = kp[d * 4096 + 192];
#pragma unroll
      for (int ii = 0; ii < 4; ++ii) {
        const float qv = q_t[(islot * 4 + ii) * 128 + d];
        e[ii][0] += qv * k0; e[ii][1] += qv * k1;
        e[ii][2] += qv * k2; e[ii][3] += qv * k3;
      }
    }
#pragma unroll
    for (int ii = 0; ii < 4; ++ii)
#pragma unroll
      for (int jj = 0; jj < 4; ++jj)
        e_buf[(islot * 4 + ii) * 257 + c_lane + 64 * jj] = e[ii][jj];

    // ---- online softmax over this 256-chunk (16 lanes per row) ----
    float vmax = -3.0e38f;
    const int erow = i_m * 257 + l16;
#pragma unroll
    for (int t = 0; t < 16; ++t) vmax = fmaxf(vmax, e_buf[erow + 16 * t]);
#pragma unroll
    for (int mm = 8; mm >= 1; mm >>= 1) vmax = fmaxf(vmax, __shfl_xor(vmax, mm, 64));
    const float mnew  = fmaxf(m_run, vmax);
    const float alpha = __expf(m_run - mnew);
    float psum = 0.f;
#pragma unroll
    for (int t = 0; t < 16; ++t) {
      const float p = __expf(e_buf[erow + 16 * t] - mnew);
      e_buf[erow + 16 * t] = p;
      psum += p;
    }
#pragma unroll
    for (int mm = 8; mm >= 1; mm >>= 1) psum += __shfl_xor(psum, mm, 64);
    l_run = l_run * alpha + psum;
    m_run = mnew;

    // ---- PV: acc[i][c] = alpha*acc + sum_j p[i][j] * V[j][c] ----
    float al[4];
#pragma unroll
    for (int g = 0; g < 4; ++g) al[g] = __shfl(alpha, g * 16, 64);
#pragma unroll
    for (int ii = 0; ii < 4; ++ii)
#pragma unroll
      for (int cc = 0; cc < 8; ++cc) acc[ii][cc] *= al[ii];
    const size_t vbase = (((size_t)b << 12) + j0) * 64 + c_lane;
    const int prow = islot * 4 * 257;
#pragma unroll 2
    for (int t = 0; t < 256; ++t) {
      const uint4 vv = vb[vbase + (size_t)t * 64];
      const float p0 = e_buf[prow + t];
      const float p1 = e_buf[prow + 257 + t];
      const float p2 = e_buf[prow + 2 * 257 + t];
      const float p3 = e_buf[prow + 3 * 257 + t];
      float vf[8];
      vf[0] = bflo(vv.x); vf[1] = bfhi(vv.x);
      vf[2] = bflo(vv.y); vf[3] = bfhi(vv.y);
      vf[4] = bflo(vv.z); vf[5] = bfhi(vv.z);
      vf[6] = bflo(vv.w); vf[7] = bfhi(vv.w);
#pragma unroll
      for (int cc = 0; cc < 8; ++cc) {
        acc[0][cc] += p0 * vf[cc];
        acc[1][cc] += p1 * vf[cc];
        acc[2][cc] += p2 * vf[cc];
        acc[3][cc] += p3 * vf[cc];
      }
    }
  }

  // ---- epilogue: out = gamma * acc/l + x, LDS transpose for coalescing ----
  __syncthreads();
  const float gv = gamF[0];
  float inv[4];
#pragma unroll
  for (int g = 0; g < 4; ++g) inv[g] = gv / __shfl(l_run, g * 16, 64);
  float* ob = e_buf;                     // reuse as [64 c][17]
  const int cl = tid >> 2;               // 0..63
  const int n4 = (tid & 3) * 4;
  for (int ch = 0; ch < 8; ++ch) {
    if ((c_lane >> 3) == ch) {
#pragma unroll
      for (int cc = 0; cc < 8; ++cc)
#pragma unroll
        for (int ii = 0; ii < 4; ++ii)
          ob[((c_lane & 7) * 8 + cc) * 17 + islot * 4 + ii] = acc[ii][cc] * inv[ii];
    }
    __syncthreads();
    {
      const int c = ch * 64 + cl;
      const size_t base = (((size_t)b * 512 + c) << 12) + n0 + n4;
      if (fp32mode) {
        const float4 xv = *(const float4*)((const float*)x + base);
        float4 ov;
        ov.x = ob[cl * 17 + n4 + 0] + xv.x;
        ov.y = ob[cl * 17 + n4 + 1] + xv.y;
        ov.z = ob[cl * 17 + n4 + 2] + xv.z;
        ov.w = ob[cl * 17 + n4 + 3] + xv.w;
        *(float4*)((float*)outp + base) = ov;
      } else {
        const ushort4 xv = *(const ushort4*)((const unsigned short*)x + base);
        ushort4 ov;
        ov.x = f2bf(ob[cl * 17 + n4 + 0] + bf2f(xv.x));
        ov.y = f2bf(ob[cl * 17 + n4 + 1] + bf2f(xv.y));
        ov.z = f2bf(ob[cl * 17 + n4 + 2] + bf2f(xv.z));
        ov.w = f2bf(ob[cl * 17 + n4 + 3] + bf2f(xv.w));
        *(ushort4*)((unsigned short*)outp + base) = ov;
      }
    }
    __syncthreads();
  }
}

extern "C" void kernel_launch(void* const* d_in, const int* in_sizes, int n_in,
                              void* d_out, int out_size, void* d_ws, size_t ws_size,
                              hipStream_t stream) {
  const void* x    = d_in[0];
  const void* dep  = d_in[1];
  const void* wq   = d_in[2];
  const void* bq   = d_in[3];
  const void* wqd  = d_in[4];
  const void* bqd  = d_in[5];
  const void* wk   = d_in[6];
  const void* bk   = d_in[7];
  const void* wkd  = d_in[8];
  const void* bkd  = d_in[9];
  const void* wv   = d_in[10];
  const void* bv   = d_in[11];
  const void* gam  = d_in[12];

  // ws layout: Whi(768K) Wlo(768K) Bcat(3K) gamF | Q fp32 @2MB (8MB) |
  //            K fp32 @10MB (8MB) | V bf16 @18MB (16MB). Total 34MB.
  unsigned short* Whi = (unsigned short*)d_ws;
  unsigned short* Wlo = Whi + (size_t)768 * 512;
  float* Bcat = (float*)(Wlo + (size_t)768 * 512);
  float* gamF = Bcat + 768;
  float* Q = (float*)((char*)d_ws + ((size_t)2 << 20));
  float* K = (float*)((char*)d_ws + ((size_t)10 << 20));
  unsigned short* V = (unsigned short*)((char*)d_ws + ((size_t)18 << 20));

  prep_kernel<<<768, 256, 0, stream>>>(wq, bq, wqd, bqd, wk, bk, wkd, bkd,
                                       wv, bv, gam, x, Whi, Wlo, Bcat, gamF);
  proj_kernel<<<dim3(128, 4), 256, 0, stream>>>(x, dep, Whi, Wlo, Bcat, Q, K, V);
  attn_kernel<<<dim3(256, 4), 256, 0, stream>>>(Q, K, V, x, gamF, d_out);
}

// Round 3
// 872.887 us; speedup vs baseline: 1.9874x; 1.9874x over previous
//
#include <hip/hip_runtime.h>

// ---------------------------------------------------------------------------
// PAM_Module_Dep: dual-modality position attention. B=4, C=512, N=4096, CQ=64.
// Round 3: MFMA flash attention.
//  - proj (MFMA, split-bf16 in fp32 mode): Q,K -> [b][n][128] bf16 hi+lo;
//    V -> [b][c][4096] bf16.
//  - attn: per block 64 Q-rows, 8 waves, two-pass:
//      pass1: row-max m-hat via hi-only MFMA energy (m-hat cancels exactly).
//      pass2: exact split energy (3 MFMA), p = bf16(exp(e-m)), l = sum of
//             ROUNDED p (normalization exact), PV as O^T = V^T * P^T so C/D
//             layout == [c][n] output layout (no epilogue transpose).
//    P via double-buffered LDS, ONE barrier per 64-j chunk.
// Dtype detection (round-2, verified) retained.
// ---------------------------------------------------------------------------

typedef __attribute__((ext_vector_type(8))) short bf16x8;
typedef __attribute__((ext_vector_type(4))) float f32x4;

__device__ __forceinline__ float bf2f(unsigned short u) {
  return __builtin_bit_cast(float, (unsigned int)u << 16);
}
__device__ __forceinline__ unsigned short f2bf(float f) {
  unsigned int u = __builtin_bit_cast(unsigned int, f);
  u = u + 0x7fffu + ((u >> 16) & 1u);   // RNE
  return (unsigned short)(u >> 16);
}
__device__ __forceinline__ float bflo(unsigned int u) {
  return __builtin_bit_cast(float, u << 16);
}

// Returns 1 if x looks like fp32 data, 0 if bf16. Wave-uniform, deterministic.
__device__ __forceinline__ int detect_fp32_mode(const void* xv) {
  const unsigned int* p = (const unsigned int*)xv;
  const int lane = threadIdx.x & 63;
  const unsigned int w0 = p[lane];
  const unsigned int w1 = p[64 + lane];
  int cnt = 0;
  const unsigned short us[4] = {
      (unsigned short)(w0 & 0xffffu), (unsigned short)(w0 >> 16),
      (unsigned short)(w1 & 0xffffu), (unsigned short)(w1 >> 16)};
#pragma unroll
  for (int h = 0; h < 4; ++h) {
    const float a = fabsf(bf2f(us[h]));
    cnt += (a > 9.0e-13f && a < 32.0f) ? 1 : 0;
  }
#pragma unroll
  for (int mm = 32; mm >= 1; mm >>= 1) cnt += __shfl_xor(cnt, mm, 64);
  return cnt < 220;
}

// ---------------------------------------------------------------------------
// prep: canonicalize weights into ws as split hi/lo bf16; biases+gamma fp32.
// Wcat rows: wq[0:64) wqd[64:128) wk[128:192) wkd[192:256) wv[256:768).
// ---------------------------------------------------------------------------
__global__ __launch_bounds__(256) void prep_kernel(
    const void* wq, const void* bq, const void* wqd, const void* bqd,
    const void* wk, const void* bk, const void* wkd, const void* bkd,
    const void* wv, const void* bv, const void* gam, const void* x,
    unsigned short* __restrict__ Whi, unsigned short* __restrict__ Wlo,
    float* __restrict__ Bcat, float* __restrict__ gamF)
{
  const int fp32mode = detect_fp32_mode(x);
  const int row = blockIdx.x;                    // 0..767
  const void* src; const void* bsrc; int srow;
  if (row < 64)       { src = wq;  bsrc = bq;  srow = row; }
  else if (row < 128) { src = wqd; bsrc = bqd; srow = row - 64; }
  else if (row < 192) { src = wk;  bsrc = bk;  srow = row - 128; }
  else if (row < 256) { src = wkd; bsrc = bkd; srow = row - 192; }
  else                { src = wv;  bsrc = bv;  srow = row - 256; }
  for (int c = threadIdx.x; c < 512; c += 256) {
    const float v = fp32mode ? ((const float*)src)[(size_t)srow * 512 + c]
                             : bf2f(((const unsigned short*)src)[(size_t)srow * 512 + c]);
    const unsigned short h = f2bf(v);
    Whi[(size_t)row * 512 + c] = h;
    Wlo[(size_t)row * 512 + c] = f2bf(v - bf2f(h));
  }
  if (threadIdx.x == 0) {
    Bcat[row] = fp32mode ? ((const float*)bsrc)[srow]
                         : bf2f(((const unsigned short*)bsrc)[srow]);
    if (row == 0)
      gamF[0] = fp32mode ? ((const float*)gam)[0]
                         : bf2f(((const unsigned short*)gam)[0]);
  }
}

// ---------------------------------------------------------------------------
// Projection GEMM tile. C/D: col=lane&15 (n), row=quad*4+reg.
// kind 0: Q -> [b][n][128] hi/lo.  kind 1: K -> same layout, K pointers.
// kind 2: V -> [b][c][4096] bf16.
// ---------------------------------------------------------------------------
__device__ __forceinline__ void do_tile(
    const unsigned short* __restrict__ Whi, const unsigned short* __restrict__ Wlo,
    const float* __restrict__ Bcat,
    const unsigned short* Xhi, const unsigned short* Xlo, int fp32mode,
    int wrow0, int kind, int d0,
    int b, int n0, int nsub, int l15, int quad,
    unsigned short* __restrict__ Qhi, unsigned short* __restrict__ Qlo,
    unsigned short* __restrict__ Khi, unsigned short* __restrict__ Klo,
    unsigned short* __restrict__ V)
{
  f32x4 acc;
#pragma unroll
  for (int r = 0; r < 4; ++r) acc[r] = Bcat[wrow0 + quad * 4 + r];
  const unsigned short* whi = Whi + (size_t)(wrow0 + l15) * 512;
  const unsigned short* wlo = Wlo + (size_t)(wrow0 + l15) * 512;
  const unsigned short* xhi = Xhi + (nsub * 16 + l15) * 520;
  const unsigned short* xlo = Xlo + (nsub * 16 + l15) * 520;
#pragma unroll
  for (int ks = 0; ks < 16; ++ks) {
    const bf16x8 ah = *(const bf16x8*)(whi + ks * 32 + quad * 8);
    const bf16x8 bh = *(const bf16x8*)(xhi + ks * 32 + quad * 8);
    acc = __builtin_amdgcn_mfma_f32_16x16x32_bf16(ah, bh, acc, 0, 0, 0);
    if (fp32mode) {
      const bf16x8 al_ = *(const bf16x8*)(wlo + ks * 32 + quad * 8);
      const bf16x8 bl  = *(const bf16x8*)(xlo + ks * 32 + quad * 8);
      acc = __builtin_amdgcn_mfma_f32_16x16x32_bf16(ah, bl, acc, 0, 0, 0);
      acc = __builtin_amdgcn_mfma_f32_16x16x32_bf16(al_, bh, acc, 0, 0, 0);
    }
  }
  const int n = n0 + nsub * 16 + l15;
  if (kind <= 1) {                     // Q or K: [b][n][128] hi/lo
    ushort4 h, l;
#pragma unroll
    for (int r = 0; r < 4; ++r) {
      const float f = acc[r];
      const unsigned short hh = f2bf(f);
      ((unsigned short*)&h)[r] = hh;
      ((unsigned short*)&l)[r] = f2bf(f - bf2f(hh));
    }
    const size_t base = (((size_t)b << 12) + n) * 128 + d0 + quad * 4;
    if (kind == 0) { *(ushort4*)(Qhi + base) = h; *(ushort4*)(Qlo + base) = l; }
    else           { *(ushort4*)(Khi + base) = h; *(ushort4*)(Klo + base) = l; }
  } else {                             // V: [b][c][4096]
#pragma unroll
    for (int r = 0; r < 4; ++r)
      V[(((size_t)b * 512 + d0 + quad * 4 + r) << 12) + n] = f2bf(acc[r]);
  }
}

__global__ __launch_bounds__(256) void proj_kernel(
    const void* __restrict__ x, const void* __restrict__ dep,
    const unsigned short* __restrict__ Whi, const unsigned short* __restrict__ Wlo,
    const float* __restrict__ Bcat,
    unsigned short* __restrict__ Qhi, unsigned short* __restrict__ Qlo,
    unsigned short* __restrict__ Khi, unsigned short* __restrict__ Klo,
    unsigned short* __restrict__ V)
{
  __shared__ unsigned short Xhi[32 * 520];
  __shared__ unsigned short Xlo[32 * 520];
  const int fp32mode = detect_fp32_mode(x);
  const int tid  = threadIdx.x;
  const int lane = tid & 63;
  const int wave = tid >> 6;
  const int l15  = lane & 15;
  const int quad = lane >> 4;
  const int nsub = wave & 1;
  const int rgrp = wave >> 1;
  const int b  = blockIdx.y;
  const int n0 = blockIdx.x * 32;

  const int cbase = tid >> 4;          // 0..15
  const int nn    = (tid & 15) * 2;

  for (int r = 0; r < 32; ++r) {
    const int c = cbase + r * 16;
    const size_t off = (((size_t)b * 512 + c) << 12) + n0 + nn;
    float v0, v1;
    if (fp32mode) {
      const float2 f2 = *(const float2*)((const float*)x + off);
      v0 = f2.x; v1 = f2.y;
    } else {
      const unsigned int v2 = *(const unsigned int*)((const unsigned short*)x + off);
      v0 = bflo(v2 & 0xffffu); v1 = bflo(v2 >> 16);
    }
    const unsigned short h0 = f2bf(v0), h1 = f2bf(v1);
    Xhi[nn * 520 + c]       = h0;
    Xhi[(nn + 1) * 520 + c] = h1;
    Xlo[nn * 520 + c]       = f2bf(v0 - bf2f(h0));
    Xlo[(nn + 1) * 520 + c] = f2bf(v1 - bf2f(h1));
  }
  __syncthreads();

  // stage-1 (from x): 40 tiles = wq(4) | wk(4) | wv(32)
  for (int rt = rgrp; rt < 40; rt += 2) {
    if (rt < 4)
      do_tile(Whi, Wlo, Bcat, Xhi, Xlo, fp32mode, rt * 16,             0, rt * 16,
              b, n0, nsub, l15, quad, Qhi, Qlo, Khi, Klo, V);
    else if (rt < 8)
      do_tile(Whi, Wlo, Bcat, Xhi, Xlo, fp32mode, 128 + (rt - 4) * 16, 1, (rt - 4) * 16,
              b, n0, nsub, l15, quad, Qhi, Qlo, Khi, Klo, V);
    else
      do_tile(Whi, Wlo, Bcat, Xhi, Xlo, fp32mode, 256 + (rt - 8) * 16, 2, (rt - 8) * 16,
              b, n0, nsub, l15, quad, Qhi, Qlo, Khi, Klo, V);
  }
  __syncthreads();

  for (int r = 0; r < 32; ++r) {
    const int c = cbase + r * 16;
    const size_t off = (((size_t)b * 512 + c) << 12) + n0 + nn;
    float v0, v1;
    if (fp32mode) {
      const float2 f2 = *(const float2*)((const float*)dep + off);
      v0 = f2.x; v1 = f2.y;
    } else {
      const unsigned int v2 = *(const unsigned int*)((const unsigned short*)dep + off);
      v0 = bflo(v2 & 0xffffu); v1 = bflo(v2 >> 16);
    }
    const unsigned short h0 = f2bf(v0), h1 = f2bf(v1);
    Xhi[nn * 520 + c]       = h0;
    Xhi[(nn + 1) * 520 + c] = h1;
    Xlo[nn * 520 + c]       = f2bf(v0 - bf2f(h0));
    Xlo[(nn + 1) * 520 + c] = f2bf(v1 - bf2f(h1));
  }
  __syncthreads();

  // stage-2 (from dep): wqd(4) | wkd(4), d-base 64
  for (int rt = rgrp; rt < 8; rt += 2) {
    if (rt < 4)
      do_tile(Whi, Wlo, Bcat, Xhi, Xlo, fp32mode, 64 + rt * 16,        0, 64 + rt * 16,
              b, n0, nsub, l15, quad, Qhi, Qlo, Khi, Klo, V);
    else
      do_tile(Whi, Wlo, Bcat, Xhi, Xlo, fp32mode, 192 + (rt - 4) * 16, 1, 64 + (rt - 4) * 16,
              b, n0, nsub, l15, quad, Qhi, Qlo, Khi, Klo, V);
  }
}

// ---------------------------------------------------------------------------
// MFMA flash attention. Block = (b, 64 Q-rows), 512 threads (8 waves).
// Wave w: energy m-tile (w&3), j-half (w>>2); PV c-chunk w*64.
// ---------------------------------------------------------------------------
__global__ __launch_bounds__(512, 2) void attn_kernel(
    const unsigned short* __restrict__ Qhi, const unsigned short* __restrict__ Qlo,
    const unsigned short* __restrict__ Khi, const unsigned short* __restrict__ Klo,
    const unsigned short* __restrict__ V,
    const void* __restrict__ x, const float* __restrict__ gamF,
    void* __restrict__ outp)
{
  __shared__ unsigned short Pbuf[2 * 64 * 72];   // [buf][i 64][j 64 +8 pad]
  __shared__ float mstat[2 * 64];
  __shared__ float lstat[2 * 64];

  const int fp32mode = detect_fp32_mode(x);
  const int tid  = threadIdx.x;
  const int lane = tid & 63;
  const int w    = tid >> 6;          // 0..7
  const int l15  = lane & 15;
  const int quad = lane >> 4;
  const int mt   = w & 3;             // energy m-tile (16 rows)
  const int jh   = w >> 2;            // j-half
  const int b    = blockIdx.y;
  const int n0   = blockIdx.x * 64;
  const int c0   = w * 64;            // PV channel chunk

  // Q fragments (this wave's 16 rows), hi+lo, 4 d-steps
  bf16x8 qh[4], ql[4];
  {
    const size_t qb = (((size_t)b << 12) + n0 + mt * 16 + l15) * 128 + quad * 8;
#pragma unroll
    for (int ds = 0; ds < 4; ++ds) {
      qh[ds] = *(const bf16x8*)(Qhi + qb + ds * 32);
      ql[ds] = *(const bf16x8*)(Qlo + qb + ds * 32);
    }
  }

  // ---- pass 1: row maxima over this wave's j-half (hi-only energy) ----
  float rmax[4] = {-3.0e38f, -3.0e38f, -3.0e38f, -3.0e38f};
  {
    const size_t kbase = (((size_t)b << 12) + jh * 2048 + l15) * 128 + quad * 8;
    for (int t = 0; t < 128; t += 2) {
      const unsigned short* k0 = Khi + kbase + (size_t)t * 2048;
      const unsigned short* k1 = k0 + 2048;
      f32x4 e0 = {0.f, 0.f, 0.f, 0.f}, e1 = {0.f, 0.f, 0.f, 0.f};
#pragma unroll
      for (int ds = 0; ds < 4; ++ds) {
        const bf16x8 kf0 = *(const bf16x8*)(k0 + ds * 32);
        const bf16x8 kf1 = *(const bf16x8*)(k1 + ds * 32);
        e0 = __builtin_amdgcn_mfma_f32_16x16x32_bf16(qh[ds], kf0, e0, 0, 0, 0);
        e1 = __builtin_amdgcn_mfma_f32_16x16x32_bf16(qh[ds], kf1, e1, 0, 0, 0);
      }
#pragma unroll
      for (int r = 0; r < 4; ++r) rmax[r] = fmaxf(rmax[r], fmaxf(e0[r], e1[r]));
    }
  }
#pragma unroll
  for (int r = 0; r < 4; ++r) {
#pragma unroll
    for (int mm = 8; mm >= 1; mm >>= 1)
      rmax[r] = fmaxf(rmax[r], __shfl_xor(rmax[r], mm, 64));
  }
  if (l15 == 0) {
#pragma unroll
    for (int r = 0; r < 4; ++r) mstat[jh * 64 + mt * 16 + quad * 4 + r] = rmax[r];
  }
  __syncthreads();
  float mh[4];
#pragma unroll
  for (int r = 0; r < 4; ++r) {
    const int i = mt * 16 + quad * 4 + r;
    mh[r] = fmaxf(mstat[i], mstat[64 + i]);
  }

  // ---- pass 2: exact energy -> p (bf16) -> LDS -> PV (O^T = V^T P^T) ----
  float lpart[4] = {0.f, 0.f, 0.f, 0.f};
  f32x4 acc[4][4];
#pragma unroll
  for (int a = 0; a < 4; ++a)
#pragma unroll
    for (int bn = 0; bn < 4; ++bn) acc[a][bn] = (f32x4){0.f, 0.f, 0.f, 0.f};

  const int jsub = jh * 32;
  const int rowbase = mt * 16 + quad * 4;

  for (int chunk = 0; chunk < 64; ++chunk) {
    const int j0  = chunk * 64;
    const int buf = (chunk & 1) * 64 * 72;
    // energy: two 16-j tiles at j0+jsub, split-exact (3 MFMAs per d-step)
    {
      const size_t kb = (((size_t)b << 12) + j0 + jsub + l15) * 128 + quad * 8;
      f32x4 e0 = {0.f, 0.f, 0.f, 0.f}, e1 = {0.f, 0.f, 0.f, 0.f};
#pragma unroll
      for (int ds = 0; ds < 4; ++ds) {
        const bf16x8 kh0 = *(const bf16x8*)(Khi + kb + ds * 32);
        const bf16x8 kl0 = *(const bf16x8*)(Klo + kb + ds * 32);
        const bf16x8 kh1 = *(const bf16x8*)(Khi + kb + 2048 + ds * 32);
        const bf16x8 kl1 = *(const bf16x8*)(Klo + kb + 2048 + ds * 32);
        e0 = __builtin_amdgcn_mfma_f32_16x16x32_bf16(qh[ds], kh0, e0, 0, 0, 0);
        e1 = __builtin_amdgcn_mfma_f32_16x16x32_bf16(qh[ds], kh1, e1, 0, 0, 0);
        e0 = __builtin_amdgcn_mfma_f32_16x16x32_bf16(qh[ds], kl0, e0, 0, 0, 0);
        e1 = __builtin_amdgcn_mfma_f32_16x16x32_bf16(qh[ds], kl1, e1, 0, 0, 0);
        e0 = __builtin_amdgcn_mfma_f32_16x16x32_bf16(ql[ds], kh0, e0, 0, 0, 0);
        e1 = __builtin_amdgcn_mfma_f32_16x16x32_bf16(ql[ds], kh1, e1, 0, 0, 0);
      }
#pragma unroll
      for (int r = 0; r < 4; ++r) {
        const float p0 = __expf(e0[r] - mh[r]);
        const float p1 = __expf(e1[r] - mh[r]);
        const unsigned short u0 = f2bf(p0);
        const unsigned short u1 = f2bf(p1);
        lpart[r] += bf2f(u0) + bf2f(u1);    // l from ROUNDED p: exact norm
        Pbuf[buf + (rowbase + r) * 72 + jsub + l15]      = u0;
        Pbuf[buf + (rowbase + r) * 72 + jsub + 16 + l15] = u1;
      }
    }
    __syncthreads();
    // PV: O^T[c][i] += V^T[c][j] * P^T[j][i]
#pragma unroll
    for (int s = 0; s < 2; ++s) {
      bf16x8 pf[4];
#pragma unroll
      for (int nt = 0; nt < 4; ++nt)
        pf[nt] = *(const bf16x8*)(Pbuf + buf + (nt * 16 + l15) * 72 + s * 32 + quad * 8);
#pragma unroll
      for (int mc = 0; mc < 4; ++mc) {
        const size_t va_off =
            (((size_t)b * 512 + c0 + mc * 16 + l15) << 12) + j0 + s * 32 + quad * 8;
        const bf16x8 va = *(const bf16x8*)(V + va_off);
#pragma unroll
        for (int nt = 0; nt < 4; ++nt)
          acc[mc][nt] = __builtin_amdgcn_mfma_f32_16x16x32_bf16(va, pf[nt], acc[mc][nt], 0, 0, 0);
      }
    }
  }

  // ---- l reduction ----
#pragma unroll
  for (int r = 0; r < 4; ++r) {
#pragma unroll
    for (int mm = 8; mm >= 1; mm >>= 1)
      lpart[r] += __shfl_xor(lpart[r], mm, 64);
  }
  if (l15 == 0) {
#pragma unroll
    for (int r = 0; r < 4; ++r) lstat[jh * 64 + rowbase + r] = lpart[r];
  }
  __syncthreads();

  // ---- epilogue: out[c][n] = gamma*O/l + x ----
  const float gv = gamF[0];
  float sc[4];
#pragma unroll
  for (int nt = 0; nt < 4; ++nt) {
    const int i = nt * 16 + l15;
    sc[nt] = gv / (lstat[i] + lstat[64 + i]);
  }
#pragma unroll
  for (int mc = 0; mc < 4; ++mc) {
#pragma unroll
    for (int r = 0; r < 4; ++r) {
      const int c_g = c0 + mc * 16 + quad * 4 + r;
      const size_t brow = ((size_t)b * 512 + c_g) << 12;
#pragma unroll
      for (int nt = 0; nt < 4; ++nt) {
        const size_t addr = brow + n0 + nt * 16 + l15;
        const float o = sc[nt] * acc[mc][nt][r];
        if (fp32mode) {
          ((float*)outp)[addr] = o + ((const float*)x)[addr];
        } else {
          ((unsigned short*)outp)[addr] =
              f2bf(o + bf2f(((const unsigned short*)x)[addr]));
        }
      }
    }
  }
}

extern "C" void kernel_launch(void* const* d_in, const int* in_sizes, int n_in,
                              void* d_out, int out_size, void* d_ws, size_t ws_size,
                              hipStream_t stream) {
  const void* x    = d_in[0];
  const void* dep  = d_in[1];
  const void* wq   = d_in[2];
  const void* bq   = d_in[3];
  const void* wqd  = d_in[4];
  const void* bqd  = d_in[5];
  const void* wk   = d_in[6];
  const void* bk   = d_in[7];
  const void* wkd  = d_in[8];
  const void* bkd  = d_in[9];
  const void* wv   = d_in[10];
  const void* bv   = d_in[11];
  const void* gam  = d_in[12];

  // ws: Whi(768K) Wlo(768K) Bcat gamF | @2M Qhi 4M | @6M Qlo 4M | @10M Khi 4M
  //     | @14M Klo 4M | @18M V 16M  (34 MB total)
  unsigned short* Whi = (unsigned short*)d_ws;
  unsigned short* Wlo = Whi + (size_t)768 * 512;
  float* Bcat = (float*)(Wlo + (size_t)768 * 512);
  float* gamF = Bcat + 768;
  unsigned short* Qhi = (unsigned short*)((char*)d_ws + ((size_t)2 << 20));
  unsigned short* Qlo = (unsigned short*)((char*)d_ws + ((size_t)6 << 20));
  unsigned short* Khi = (unsigned short*)((char*)d_ws + ((size_t)10 << 20));
  unsigned short* Klo = (unsigned short*)((char*)d_ws + ((size_t)14 << 20));
  unsigned short* V   = (unsigned short*)((char*)d_ws + ((size_t)18 << 20));

  prep_kernel<<<768, 256, 0, stream>>>(wq, bq, wqd, bqd, wk, bk, wkd, bkd,
                                       wv, bv, gam, x, Whi, Wlo, Bcat, gamF);
  proj_kernel<<<dim3(128, 4), 256, 0, stream>>>(x, dep, Whi, Wlo, Bcat,
                                                Qhi, Qlo, Khi, Klo, V);
  attn_kernel<<<dim3(64, 4), 512, 0, stream>>>(Qhi, Qlo, Khi, Klo, V, x, gamF, d_out);
}